// Round 10
// baseline (25.278 us; speedup 1.0000x reference)
//
#include <hip/hip_runtime.h>
#include <math.h>

#define EPS 1e-6f
#define BN_EPSF 1e-5f
#define PI2F 6.2831853071795864769f
#define LOG2EF 1.4426950408889634f
#define NBB 4
#define NCC 512
#define NGG 2048
#define OUTC 64
#define NBAS 10

// d_out layout (floats): y_out, n_f, fourier_prior, n_h1, h0_f
#define Y_OFF   0
#define NF_OFF  (NBB*NGG*OUTC)          // 524288
#define FP_OFF  (NF_OFF  + NBB*NGG*9)   // 598016
#define NH1_OFF (FP_OFF  + NBB*NGG*9)   // 671744
#define H0_OFF  (NH1_OFF + NBB*NGG*9)   // 745472

// ws layout (floats)
#define WS_PRE   0                      // NBB*9*NGG = 73728
#define WS_CONV  (NBB*9*NGG)            // 73728
#define WS_STATS (2*NBB*9*NGG)          // 9 cps * 32 blocks * {sum,sumsq}

#if defined(__has_builtin)
# if __has_builtin(__builtin_amdgcn_exp2f)
#  define EXP2F(x) __builtin_amdgcn_exp2f(x)
# endif
#endif
#ifndef EXP2F
# define EXP2F(x) exp2f(x)
#endif

// ---------------------------------------------------------------------------
// K1: RBF sums + Fourier prior for 8 own g (no halo). 1024 blocks
// (4 b x 256 tiles of 8 g) x 256 threads = 4 blocks/CU = 4 waves/SIMD.
//
// LDS context layout is SKEWED, not rotated (round-9 lesson: the (i+cA)&31
// rotation made every LDS address data-dependent -> no immediate offsets,
// no load pipelining). Context point n lives at float offset
// n*8 + (n>>5)*4 (16 B skew per 32 points): the wave's 8 broadcast groups
// land on banks {0,0,4,4,8,8,12,12} = 2-way (free, m136), and the in-chunk
// address is affine in i -> ds_read_b128 with immediate offsets.
// p-inner: 18 accumulators (proven non-spilling at 256 thr).
// ---------------------------------------------------------------------------
__global__ __launch_bounds__(256) void k1_rbf(
    const float* __restrict__ x_c, const float* __restrict__ y_c,
    const float* __restrict__ x_g, const float* __restrict__ sigma,
    const float* __restrict__ mu, const float* __restrict__ eps1,
    const float* __restrict__ b_u, const float* __restrict__ random_w,
    float* __restrict__ out, float* __restrict__ ws)
{
    const int bid = blockIdx.x;
    const int b = bid >> 8;            // 4 b x 256 tiles of 8 g
    const int gtile = bid & 255;
    const int g0 = gtile * 8;
    const int tid = threadIdx.x;

    __shared__ float cxy[NCC*8 + (NCC/32)*4];  // 16.6 KB skewed (x0,y0,x1,y1,x2,y2,-,-)
    __shared__ float red[32][8][19];           // 19.5 KB chunk partials (+1 pad)
    __shared__ float sw_l[NBAS*3], sb_l[NBAS*3], rw_l[NBAS];

    // ---- stage context set + small params ----
    const float* xcb = x_c + b*NCC*3;
    const float* ycb = y_c + b*NCC*3;
    for (int i = tid; i < NCC*3; i += 256) {
        int n = i/3, c = i - n*3;
        int base = n*8 + ((n>>5)<<2);
        cxy[base + 2*c]     = xcb[i];
        cxy[base + 2*c + 1] = ycb[i];
    }
    if (tid < NBAS*3) {
        int k = tid/3, p = tid - k*3;
        float wmu  = expf(mu[p]);
        float wstd = 1.0f / (expf(sigma[p]) + EPS);
        sw_l[tid] = wmu + wstd * eps1[(b*NBAS + k)*3 + p];
        sb_l[tid] = PI2F * b_u[(b*NBAS + k)*3 + p];
    }
    if (tid < NBAS) rw_l[tid] = random_w[tid];

    float coef[3];
    #pragma unroll
    for (int p = 0; p < 3; ++p) {
        float s = expf(sigma[p]) + EPS;
        coef[p] = (-0.5f * LOG2EF) / (s*s);   // exp(-0.5 d^2) == exp2(d^2*coef)
    }

    // ---- mapping: g = tid&7, chunk cA = tid>>3 (32 chunks of 16 ctx) ----
    const int gA = tid & 7;
    const int cA = tid >> 3;
    const float xg0 = x_g[(b*NGG + g0 + gA)*3 + 0];
    const float xg1 = x_g[(b*NGG + g0 + gA)*3 + 1];
    const float xg2 = x_g[(b*NGG + g0 + gA)*3 + 2];

    __syncthreads();

    // ---- RBF inner loop: 16 ctx per thread, 9 exp per iter, affine LDS ----
    float h0a[3][3] = {{0}}, h1a[3][3] = {{0}};
    const int fbase = cA*128 + ((cA>>1)<<2);   // chunk base (16 ctx, skew-aligned)
    #pragma unroll 4
    for (int i = 0; i < 16; ++i) {
        float4 A = *(const float4*)&cxy[fbase + i*8];
        float4 B = *(const float4*)&cxy[fbase + i*8 + 4];
        float d0 = A.x - xg0, d1 = A.z - xg1, d2 = B.x - xg2;
        float dx2[3] = {d0*d0, d1*d1, d2*d2};
        float yv[3]  = {A.y, A.w, B.y};
        #pragma unroll
        for (int c = 0; c < 3; ++c)
            #pragma unroll
            for (int p = 0; p < 3; ++p) {
                float w = EXP2F(dx2[c] * coef[p]);
                h0a[c][p] += w;
                h1a[c][p] += w * yv[c];
            }
    }
    #pragma unroll
    for (int c = 0; c < 3; ++c)
        #pragma unroll
        for (int p = 0; p < 3; ++p) {
            red[cA][gA][c*3 + p]     = h0a[c][p];
            red[cA][gA][9 + c*3 + p] = h1a[c][p];
        }
    __syncthreads();

    // ---- finalize 8*9 = 72 outputs: reduce 32 chunks + Fourier prior ----
    if (tid < 72) {
        int gl = tid / 9, cp = tid - gl*9;
        int c = cp / 3, p = cp - c*3;
        float h0 = 0.f, h1 = 0.f;
        #pragma unroll 8
        for (int q = 0; q < 32; ++q) {
            h0 += red[q][gl][cp];
            h1 += red[q][gl][9 + cp];
        }
        float nh1 = h1 / (h0 + EPS);
        float xg = x_g[(b*NGG + g0 + gl)*3 + c];
        float fp = 0.f;
        #pragma unroll
        for (int k = 0; k < NBAS; ++k) {
            // match numpy rounding: separate mul + add (no fma contraction)
            float arg = __fadd_rn(__fmul_rn(sw_l[k*3 + p], xg), sb_l[k*3 + p]);
            fp += rw_l[k] * cosf(arg);   // args reach ~4e4: keep accurate cosf
        }
        fp *= 0.44721359549995793f;      // sqrt(2/10)
        int base = (b*NGG + g0 + gl)*9 + cp;
        out[H0_OFF  + base] = h0;
        out[NH1_OFF + base] = nh1;
        out[FP_OFF  + base] = fp;
        ws[WS_PRE + (b*9 + cp)*NGG + g0 + gl] = nh1 + fp;
    }
}

// ---------------------------------------------------------------------------
// K2: depthwise conv along g + deterministic BN partial stats.
// 288 blocks (4 b x 9 cp x 8 g-chunks) x 256 threads.
// ---------------------------------------------------------------------------
__global__ __launch_bounds__(256) void k2_conv(
    const float* __restrict__ cw1, const float* __restrict__ cb1,
    const float* __restrict__ cw2, const float* __restrict__ cb2,
    const float* __restrict__ cw3, const float* __restrict__ cb3,
    float* __restrict__ ws)
{
    int bid = blockIdx.x;                 // nb*9*8 = 288
    int b = bid / 72; int r = bid - b*72;
    int cp = r / 8;  int gc = r - cp*8;
    int g = gc*256 + threadIdx.x;
    int c = cp / 3, p = cp - c*3;
    const float* pre = ws + WS_PRE + (b*9 + cp)*NGG;

    int K, pad; const float* w; float bias;
    if (p == 0)      { K = 3; pad = 1; w = cw1 + c*3; bias = cb1[c]; }
    else if (p == 1) { K = 5; pad = 2; w = cw2 + c*5; bias = cb2[c]; }
    else             { K = 9; pad = 4; w = cw3 + c*9; bias = cb3[c]; }

    float acc = bias;
    for (int k = 0; k < K; ++k) {
        int idx = g - pad + k;
        if (idx >= 0 && idx < NGG) acc += w[k] * pre[idx];
    }
    ws[WS_CONV + (b*9 + cp)*NGG + g] = acc;

    // BN stats: block reduce -> deterministic per-block partial (no atomics)
    float s1 = acc, s2 = acc*acc;
    #pragma unroll
    for (int o = 32; o > 0; o >>= 1) {
        s1 += __shfl_down(s1, o);
        s2 += __shfl_down(s2, o);
    }
    __shared__ float r1[4], r2[4];
    int lane = threadIdx.x & 63, wv = threadIdx.x >> 6;
    if (lane == 0) { r1[wv] = s1; r2[wv] = s2; }
    __syncthreads();
    if (threadIdx.x == 0) {
        float t1 = r1[0] + r1[1] + r1[2] + r1[3];
        float t2 = r2[0] + r2[1] + r2[2] + r2[3];
        int pidx = cp*32 + b*8 + gc;
        ws[WS_STATS + pidx*2]     = t1;
        ws[WS_STATS + pidx*2 + 1] = t2;
    }
}

// ---------------------------------------------------------------------------
// K3: BN stats reduce + normalize (n_f) + output GEMV. 2048 blocks x 256.
// ---------------------------------------------------------------------------
__global__ __launch_bounds__(256) void k3_out(
    const float* __restrict__ bn_gamma, const float* __restrict__ bn_beta,
    const float* __restrict__ g_w, const float* __restrict__ g_b,
    float* __restrict__ out, float* __restrict__ ws)
{
    __shared__ float gw_l[OUTC*18];
    __shared__ float feat_l[4][18];
    __shared__ float ps[9][16][2];
    __shared__ float mstat[9][2];
    const int tid = threadIdx.x;

    for (int i = tid; i < OUTC*18; i += 256) gw_l[i] = g_w[i];
    if (tid < 144) {
        int cp = tid / 16, q = tid & 15;
        int idx = WS_STATS + (cp*32 + 2*q)*2;
        ps[cp][q][0] = ws[idx]     + ws[idx + 2];
        ps[cp][q][1] = ws[idx + 1] + ws[idx + 3];
    }
    __syncthreads();
    if (tid < 9) {
        float s1 = 0.f, s2 = 0.f;
        #pragma unroll
        for (int q = 0; q < 16; ++q) { s1 += ps[tid][q][0]; s2 += ps[tid][q][1]; }
        float mean = s1 * (1.0f/8192.0f);
        float var  = s2 * (1.0f/8192.0f) - mean*mean;
        mstat[tid][0] = mean;
        mstat[tid][1] = rsqrtf(var + BN_EPSF);
    }
    __syncthreads();

    if (tid < 72) {
        int pt = tid / 18, j = tid - pt*18;
        int P = blockIdx.x*4 + pt;
        int b = P >> 11, g = P & 2047;
        float f;
        if (j < 9) {
            f = out[H0_OFF + (b*NGG + g)*9 + j];
        } else {
            int cp = j - 9; int c = cp / 3, p = cp - c*3;
            float x = ws[WS_CONV + (b*9 + cp)*NGG + g];
            float v = bn_gamma[p*3 + c] * (x - mstat[cp][0]) * mstat[cp][1]
                      + bn_beta[p*3 + c];
            out[NF_OFF + (b*NGG + g)*9 + cp] = v;
            f = v;
        }
        feat_l[pt][j] = f;
    }
    __syncthreads();

    int pt = tid >> 6, o = tid & 63;
    int P = blockIdx.x*4 + pt;
    int b = P >> 11, g = P & 2047;
    float acc = g_b[o];
    #pragma unroll
    for (int j = 0; j < 18; ++j) acc += feat_l[pt][j] * gw_l[o*18 + j];
    out[Y_OFF + (b*NGG + g)*OUTC + o] = acc;
}

extern "C" void kernel_launch(void* const* d_in, const int* in_sizes, int n_in,
                              void* d_out, int out_size, void* d_ws, size_t ws_size,
                              hipStream_t stream)
{
    const float* x_c      = (const float*)d_in[0];
    const float* y_c      = (const float*)d_in[1];
    const float* x_g      = (const float*)d_in[2];
    const float* sigma    = (const float*)d_in[3];
    const float* mu       = (const float*)d_in[4];
    const float* eps1     = (const float*)d_in[5];
    const float* b_u      = (const float*)d_in[6];
    const float* random_w = (const float*)d_in[7];
    const float* conv_w1  = (const float*)d_in[8];
    const float* conv_b1  = (const float*)d_in[9];
    const float* conv_w2  = (const float*)d_in[10];
    const float* conv_b2  = (const float*)d_in[11];
    const float* conv_w3  = (const float*)d_in[12];
    const float* conv_b3  = (const float*)d_in[13];
    const float* bn_gamma = (const float*)d_in[14];
    const float* bn_beta  = (const float*)d_in[15];
    const float* g_w      = (const float*)d_in[16];
    const float* g_b      = (const float*)d_in[17];

    float* outp = (float*)d_out;
    float* wsp  = (float*)d_ws;

    k1_rbf<<<NBB*256, 256, 0, stream>>>(x_c, y_c, x_g, sigma, mu, eps1, b_u,
                                        random_w, outp, wsp);
    k2_conv<<<NBB*9*(NGG/256), 256, 0, stream>>>(conv_w1, conv_b1, conv_w2, conv_b2,
                                                 conv_w3, conv_b3, wsp);
    k3_out<<<(NBB*NGG)/4, 256, 0, stream>>>(bn_gamma, bn_beta, g_w, g_b, outp, wsp);
}

// Round 11
// 23.774 us; speedup vs baseline: 1.0633x; 1.0633x over previous
//
#include <hip/hip_runtime.h>
#include <math.h>

#define EPS 1e-6f
#define BN_EPSF 1e-5f
#define PI2F 6.2831853071795864769f
#define INV2PIF 0.15915494309189535f
#define LOG2EF 1.4426950408889634f
#define NBB 4
#define NCC 512
#define NGG 2048
#define OUTC 64
#define NBAS 10

// d_out layout (floats): y_out, n_f, fourier_prior, n_h1, h0_f
#define Y_OFF   0
#define NF_OFF  (NBB*NGG*OUTC)          // 524288
#define FP_OFF  (NF_OFF  + NBB*NGG*9)   // 598016
#define NH1_OFF (FP_OFF  + NBB*NGG*9)   // 671744
#define H0_OFF  (NH1_OFF + NBB*NGG*9)   // 745472

// ws layout (floats)
#define WSH0     0                      // raw h0 sums, NBB*9*NGG = 73728
#define WSH1     (NBB*9*NGG)            // raw h1 sums
#define WS_CONV  (2*NBB*9*NGG)          // conv outputs
#define WS_STATS (3*NBB*9*NGG)          // 9 cps * 32 blocks * {sum,sumsq}

#if defined(__has_builtin)
# if __has_builtin(__builtin_amdgcn_exp2f)
#  define EXP2F(x) __builtin_amdgcn_exp2f(x)
# endif
# if __has_builtin(__builtin_amdgcn_cosf)
#  define COS_REV(r) __builtin_amdgcn_cosf(r)   // cos(2*pi*r), r in [0,1)
# endif
#endif
#ifndef EXP2F
# define EXP2F(x) exp2f(x)
#endif
#ifndef COS_REV
# define COS_REV(r) cosf(PI2F*(r))
#endif

// ---------------------------------------------------------------------------
// K1: PURE RBF partial sums for 8 g. 1024 blocks (4 b x 256 tiles) x 256 thr,
// 4 blocks/CU. No cos, no outputs — just h0,h1 -> ws. (Round-10 lesson: k1's
// residual was occupancy/addressing-invariant; prime suspect is the OCML
// cosf Payne-Hanek tail, now evicted from this kernel entirely.)
// Skewed LDS: ctx n at float offset n*8 + (n>>5)*4 -> affine addresses,
// 2-way broadcast banks (free).
// ---------------------------------------------------------------------------
__global__ __launch_bounds__(256) void k1_rbf(
    const float* __restrict__ x_c, const float* __restrict__ y_c,
    const float* __restrict__ x_g, const float* __restrict__ sigma,
    float* __restrict__ ws)
{
    const int bid = blockIdx.x;
    const int b = bid >> 8;            // 4 b x 256 tiles of 8 g
    const int gtile = bid & 255;
    const int g0 = gtile * 8;
    const int tid = threadIdx.x;

    __shared__ float cxy[NCC*8 + (NCC/32)*4];  // 16.6 KB skewed (x0,y0,x1,y1,x2,y2,-,-)
    __shared__ float red[32][8][19];           // 19 KB chunk partials (+1 pad)

    const float* xcb = x_c + b*NCC*3;
    const float* ycb = y_c + b*NCC*3;
    for (int i = tid; i < NCC*3; i += 256) {
        int n = i/3, c = i - n*3;
        int base = n*8 + ((n>>5)<<2);
        cxy[base + 2*c]     = xcb[i];
        cxy[base + 2*c + 1] = ycb[i];
    }

    float coef[3];
    #pragma unroll
    for (int p = 0; p < 3; ++p) {
        float s = expf(sigma[p]) + EPS;
        coef[p] = (-0.5f * LOG2EF) / (s*s);   // exp(-0.5 d^2) == exp2(d^2*coef)
    }

    const int gA = tid & 7;
    const int cA = tid >> 3;           // 32 chunks of 16 ctx
    const float xg0 = x_g[(b*NGG + g0 + gA)*3 + 0];
    const float xg1 = x_g[(b*NGG + g0 + gA)*3 + 1];
    const float xg2 = x_g[(b*NGG + g0 + gA)*3 + 2];

    __syncthreads();

    float h0a[3][3] = {{0}}, h1a[3][3] = {{0}};
    const int fbase = cA*128 + ((cA>>1)<<2);   // chunk base (16 ctx, skew-aligned)
    #pragma unroll 4
    for (int i = 0; i < 16; ++i) {
        float4 A = *(const float4*)&cxy[fbase + i*8];
        float4 B = *(const float4*)&cxy[fbase + i*8 + 4];
        float d0 = A.x - xg0, d1 = A.z - xg1, d2 = B.x - xg2;
        float dx2[3] = {d0*d0, d1*d1, d2*d2};
        float yv[3]  = {A.y, A.w, B.y};
        #pragma unroll
        for (int c = 0; c < 3; ++c)
            #pragma unroll
            for (int p = 0; p < 3; ++p) {
                float w = EXP2F(dx2[c] * coef[p]);
                h0a[c][p] += w;
                h1a[c][p] += w * yv[c];
            }
    }
    #pragma unroll
    for (int c = 0; c < 3; ++c)
        #pragma unroll
        for (int p = 0; p < 3; ++p) {
            red[cA][gA][c*3 + p]     = h0a[c][p];
            red[cA][gA][9 + c*3 + p] = h1a[c][p];
        }
    __syncthreads();

    // reduce 32 chunks -> raw h0,h1 to ws (72 items; no transcendentals here)
    if (tid < 72) {
        int gl = tid / 9, cp = tid - gl*9;
        float h0 = 0.f, h1 = 0.f;
        #pragma unroll 8
        for (int q = 0; q < 32; ++q) {
            h0 += red[q][gl][cp];
            h1 += red[q][gl][9 + cp];
        }
        int idx = (b*9 + cp)*NGG + g0 + gl;
        ws[WSH0 + idx] = h0;
        ws[WSH1 + idx] = h1;
    }
}

// ---------------------------------------------------------------------------
// K2: finalize (nh1 + Fourier prior via HW cos) for 256 own g + 8 halo g,
// then depthwise conv + BN partials. 288 blocks (4 b x 9 cp x 8 gc) x 256.
// Halo here is just 8 extra finalizes (reads + 80 hw-cos) — cheap, unlike
// the RBF-halo recompute that failed in rounds 5-8.
// ---------------------------------------------------------------------------
__global__ __launch_bounds__(256) void k2_fin_conv(
    const float* __restrict__ x_g, const float* __restrict__ sigma,
    const float* __restrict__ mu, const float* __restrict__ eps1,
    const float* __restrict__ b_u, const float* __restrict__ random_w,
    const float* __restrict__ cw1, const float* __restrict__ cb1,
    const float* __restrict__ cw2, const float* __restrict__ cb2,
    const float* __restrict__ cw3, const float* __restrict__ cb3,
    float* __restrict__ out, float* __restrict__ ws)
{
    const int bid = blockIdx.x;           // 4b x 9cp x 8gc = 288
    const int b = bid / 72; int r = bid - b*72;
    const int cp = r >> 3;  const int gc = r & 7;
    const int c = cp / 3, p = cp - c*3;
    const int tid = threadIdx.x;

    __shared__ float pre_l[264];          // 0..3 left halo, 4..259 own, 260..263 right
    __shared__ float swl[NBAS], sbl[NBAS], rwl[NBAS];
    __shared__ float r1[4], r2[4];

    if (tid < NBAS) {
        float wmu  = expf(mu[p]);
        float wstd = 1.0f / (expf(sigma[p]) + EPS);
        swl[tid] = wmu + wstd * eps1[(b*NBAS + tid)*3 + p];
        sbl[tid] = PI2F * b_u[(b*NBAS + tid)*3 + p];
        rwl[tid] = random_w[tid];
    }
    __syncthreads();

    for (int s = tid; s < 264; s += 256) {
        int gf = gc*256 - 4 + s;
        float v = 0.f;
        if (gf >= 0 && gf < NGG) {
            int idx = (b*9 + cp)*NGG + gf;
            float h0 = ws[WSH0 + idx];
            float h1 = ws[WSH1 + idx];
            float nh1 = h1 / (h0 + EPS);
            float xg = x_g[(b*NGG + gf)*3 + c];
            float fp = 0.f;
            #pragma unroll
            for (int k = 0; k < NBAS; ++k) {
                // arg bits match numpy (mul+add, round-to-nearest);
                // cos via HW: cos(arg) = v_cos(fract(arg/2pi)); reduction
                // error <= ~0.012 rad at |arg|<=1.5e5 — inside threshold.
                float arg = __fadd_rn(__fmul_rn(swl[k], xg), sbl[k]);
                float rev = arg * INV2PIF;
                rev = rev - floorf(rev);
                fp += rwl[k] * COS_REV(rev);
            }
            fp *= 0.44721359549995793f;   // sqrt(2/10)
            v = nh1 + fp;
            if (s >= 4 && s < 260) {      // own range: write the three outputs
                int obase = (b*NGG + gf)*9 + cp;
                out[H0_OFF  + obase] = h0;
                out[NH1_OFF + obase] = nh1;
                out[FP_OFF  + obase] = fp;
            }
        }
        pre_l[s] = v;                     // zero beyond grid edges (conv zero-pad)
    }
    __syncthreads();

    // depthwise conv (own 256 g) + deterministic BN partials
    int K, pad; const float* w; float bias;
    if (p == 0)      { K = 3; pad = 1; w = cw1 + c*3; bias = cb1[c]; }
    else if (p == 1) { K = 5; pad = 2; w = cw2 + c*5; bias = cb2[c]; }
    else             { K = 9; pad = 4; w = cw3 + c*9; bias = cb3[c]; }

    float acc = bias;
    for (int k = 0; k < K; ++k)
        acc += w[k] * pre_l[tid + 4 - pad + k];
    ws[WS_CONV + (b*9 + cp)*NGG + gc*256 + tid] = acc;

    float s1 = acc, s2 = acc*acc;
    #pragma unroll
    for (int o = 32; o > 0; o >>= 1) {
        s1 += __shfl_down(s1, o);
        s2 += __shfl_down(s2, o);
    }
    int lane = tid & 63, wv = tid >> 6;
    if (lane == 0) { r1[wv] = s1; r2[wv] = s2; }
    __syncthreads();
    if (tid == 0) {
        float t1 = r1[0] + r1[1] + r1[2] + r1[3];
        float t2 = r2[0] + r2[1] + r2[2] + r2[3];
        int pidx = cp*32 + b*8 + gc;
        ws[WS_STATS + pidx*2]     = t1;
        ws[WS_STATS + pidx*2 + 1] = t2;
    }
}

// ---------------------------------------------------------------------------
// K3: BN stats reduce + normalize (n_f) + output GEMV. 2048 blocks x 256.
// ---------------------------------------------------------------------------
__global__ __launch_bounds__(256) void k3_out(
    const float* __restrict__ bn_gamma, const float* __restrict__ bn_beta,
    const float* __restrict__ g_w, const float* __restrict__ g_b,
    float* __restrict__ out, float* __restrict__ ws)
{
    __shared__ float4 gw4[OUTC*18/4];     // float4-staged g_w
    __shared__ float feat_l[4][18];
    __shared__ float ps[9][16][2];
    __shared__ float mstat[9][2];
    const int tid = threadIdx.x;
    float* gw_l = (float*)gw4;

    for (int i = tid; i < OUTC*18/4; i += 256)
        gw4[i] = ((const float4*)g_w)[i];
    if (tid < 144) {
        int cp = tid / 16, q = tid & 15;
        int idx = WS_STATS + (cp*32 + 2*q)*2;
        ps[cp][q][0] = ws[idx]     + ws[idx + 2];
        ps[cp][q][1] = ws[idx + 1] + ws[idx + 3];
    }
    __syncthreads();
    if (tid < 9) {
        float s1 = 0.f, s2 = 0.f;
        #pragma unroll
        for (int q = 0; q < 16; ++q) { s1 += ps[tid][q][0]; s2 += ps[tid][q][1]; }
        float mean = s1 * (1.0f/8192.0f);
        float var  = s2 * (1.0f/8192.0f) - mean*mean;
        mstat[tid][0] = mean;
        mstat[tid][1] = rsqrtf(var + BN_EPSF);
    }
    __syncthreads();

    if (tid < 72) {
        int pt = tid / 18, j = tid - pt*18;
        int P = blockIdx.x*4 + pt;
        int b = P >> 11, g = P & 2047;
        float f;
        if (j < 9) {
            f = out[H0_OFF + (b*NGG + g)*9 + j];
        } else {
            int cp = j - 9; int c = cp / 3, p = cp - c*3;
            float x = ws[WS_CONV + (b*9 + cp)*NGG + g];
            float v = bn_gamma[p*3 + c] * (x - mstat[cp][0]) * mstat[cp][1]
                      + bn_beta[p*3 + c];
            out[NF_OFF + (b*NGG + g)*9 + cp] = v;
            f = v;
        }
        feat_l[pt][j] = f;
    }
    __syncthreads();

    int pt = tid >> 6, o = tid & 63;
    int P = blockIdx.x*4 + pt;
    int b = P >> 11, g = P & 2047;
    float acc = g_b[o];
    #pragma unroll
    for (int j = 0; j < 18; ++j) acc += feat_l[pt][j] * gw_l[o*18 + j];
    out[Y_OFF + (b*NGG + g)*OUTC + o] = acc;
}

extern "C" void kernel_launch(void* const* d_in, const int* in_sizes, int n_in,
                              void* d_out, int out_size, void* d_ws, size_t ws_size,
                              hipStream_t stream)
{
    const float* x_c      = (const float*)d_in[0];
    const float* y_c      = (const float*)d_in[1];
    const float* x_g      = (const float*)d_in[2];
    const float* sigma    = (const float*)d_in[3];
    const float* mu       = (const float*)d_in[4];
    const float* eps1     = (const float*)d_in[5];
    const float* b_u      = (const float*)d_in[6];
    const float* random_w = (const float*)d_in[7];
    const float* conv_w1  = (const float*)d_in[8];
    const float* conv_b1  = (const float*)d_in[9];
    const float* conv_w2  = (const float*)d_in[10];
    const float* conv_b2  = (const float*)d_in[11];
    const float* conv_w3  = (const float*)d_in[12];
    const float* conv_b3  = (const float*)d_in[13];
    const float* bn_gamma = (const float*)d_in[14];
    const float* bn_beta  = (const float*)d_in[15];
    const float* g_w      = (const float*)d_in[16];
    const float* g_b      = (const float*)d_in[17];

    float* outp = (float*)d_out;
    float* wsp  = (float*)d_ws;

    k1_rbf<<<NBB*256, 256, 0, stream>>>(x_c, y_c, x_g, sigma, wsp);
    k2_fin_conv<<<NBB*9*(NGG/256), 256, 0, stream>>>(x_g, sigma, mu, eps1, b_u,
                                                     random_w, conv_w1, conv_b1,
                                                     conv_w2, conv_b2, conv_w3,
                                                     conv_b3, outp, wsp);
    k3_out<<<(NBB*NGG)/4, 256, 0, stream>>>(bn_gamma, bn_beta, g_w, g_b, outp, wsp);
}